// Round 13
// baseline (118.984 us; speedup 1.0000x reference)
//
#include <hip/hip_runtime.h>
#include <hip/hip_bf16.h>

#define SDIM 1024
#define HNUM 8
#define DDIM 64
#define EMBD 512
#define NBATCH 8

static constexpr float SCALE = 0.044194173824159216f; // 1/sqrt(512)

typedef short bf16x8 __attribute__((ext_vector_type(8)));
typedef float f32x4 __attribute__((ext_vector_type(4)));

__device__ __forceinline__ ushort bf16_of(float f) {
    return __builtin_bit_cast(unsigned short, __float2bfloat16(f));
}
__device__ __forceinline__ float f32_of(ushort u) {
    return __bfloat162float(__builtin_bit_cast(__hip_bfloat16, u));
}

// swizzled LDS tile access: rows of 64 bf16 = 8 chunks of 16B; chunk (row,slot)
// stored at slot ^ (row&7) -> conflict-free ds_read_b128 column walks.
// One row = 8 chunks * 8 ushorts = 64 ushorts.
__device__ __forceinline__ bf16x8 lds8(const ushort* base, int row, int slot) {
    return *(const bf16x8*)(base + (row * 8 + (slot ^ (row & 7))) * 8);
}

#define MFMA(a, b, c) __builtin_amdgcn_mfma_f32_16x16x32_bf16(a, b, c, 0, 0, 0)

// ---------------------------------------------------------------------------
// Kernel A (MFMA): per-head projections -> bf16, h-major layout [n][h][s][d].
// m==0 blocks additionally emit the transposed V panels [n][h][d][s].
// ---------------------------------------------------------------------------
__global__ __launch_bounds__(256) void proj_mfma(
    const float* __restrict__ xv, const float* __restrict__ xk, const float* __restrict__ xq,
    const float* __restrict__ Wv, const float* __restrict__ bv,
    const float* __restrict__ Wk, const float* __restrict__ bk,
    const float* __restrict__ Wq, const float* __restrict__ bq,
    ushort* __restrict__ vals_bf, ushort* __restrict__ keys_bf, ushort* __restrict__ qrs_bf,
    ushort* __restrict__ valsT_bf)
{
    __shared__ ushort a_s[256 * 64];   // 32 KB (also reused for C)
    __shared__ ushort w_s[64 * 64];    // 8 KB

    const int blk = blockIdx.x;        // 768 = 3 * 256
    const int m = blk % 3;
    const int chunk = blk / 3;
    const int tok0 = chunk * 32;
    const int n = tok0 >> 10, s0 = tok0 & 1023;
    const int t = threadIdx.x;
    const int w = t >> 6, l = t & 63, lrow = l & 15, lgrp = l >> 4;

    const float* X = (m == 0) ? xv : (m == 1) ? xk : xq;
    const float* W = (m == 0) ? Wv : (m == 1) ? Wk : Wq;
    const float* B = (m == 0) ? bv : (m == 1) ? bk : bq;
    ushort* O = (m == 0) ? vals_bf : (m == 1) ? keys_bf : qrs_bf;

    #pragma unroll
    for (int i = 0; i < 16; ++i) {
        const int f4 = i * 256 + t;            // 0..4095
        const int ls = f4 >> 7, c4 = f4 & 127;
        const int h = c4 >> 4, d4 = c4 & 15;
        const float4 v = ((const float4*)(X + (size_t)(tok0 + ls) * EMBD))[c4];
        ushort4 u;
        u.x = bf16_of(v.x); u.y = bf16_of(v.y); u.z = bf16_of(v.z); u.w = bf16_of(v.w);
        const int r = h * 32 + ls, slot = d4 >> 1;
        *(ushort4*)(a_s + (r * 8 + (slot ^ (r & 7))) * 8 + (d4 & 1) * 4) = u;
    }
    #pragma unroll
    for (int i = 0; i < 4; ++i) {
        const int f4 = i * 256 + t;            // 0..1023
        const int r = f4 >> 4, d4 = f4 & 15;
        const float4 v = ((const float4*)W)[f4];
        ushort4 u;
        u.x = bf16_of(v.x); u.y = bf16_of(v.y); u.z = bf16_of(v.z); u.w = bf16_of(v.w);
        const int slot = d4 >> 1;
        *(ushort4*)(w_s + (r * 8 + (slot ^ (r & 7))) * 8 + (d4 & 1) * 4) = u;
    }
    __syncthreads();

    f32x4 acc[4][4];
    #pragma unroll
    for (int fr = 0; fr < 4; ++fr)
        #pragma unroll
        for (int fc = 0; fc < 4; ++fc) acc[fr][fc] = {0.f, 0.f, 0.f, 0.f};

    bf16x8 af[4][2];
    #pragma unroll
    for (int fr = 0; fr < 4; ++fr)
        #pragma unroll
        for (int kc = 0; kc < 2; ++kc)
            af[fr][kc] = lds8(a_s, w * 64 + fr * 16 + lrow, lgrp + kc * 4);

    #pragma unroll
    for (int fc = 0; fc < 4; ++fc)
        #pragma unroll
        for (int kc = 0; kc < 2; ++kc) {
            const bf16x8 bfr = lds8(w_s, fc * 16 + lrow, lgrp + kc * 4);
            #pragma unroll
            for (int fr = 0; fr < 4; ++fr)
                acc[fr][fc] = MFMA(af[fr][kc], bfr, acc[fr][fc]);
        }
    __syncthreads();

    float bias[4];
    #pragma unroll
    for (int fc = 0; fc < 4; ++fc) bias[fc] = B[fc * 16 + lrow];
    #pragma unroll
    for (int fr = 0; fr < 4; ++fr)
        #pragma unroll
        for (int fc = 0; fc < 4; ++fc)
            #pragma unroll
            for (int reg = 0; reg < 4; ++reg) {
                const int row = w * 64 + fr * 16 + lgrp * 4 + reg;
                const int col = fc * 16 + lrow;
                a_s[(row * 8 + ((col >> 3) ^ (row & 7))) * 8 + (col & 7)] =
                    bf16_of(acc[fr][fc][reg] + bias[fc]);
            }
    __syncthreads();

    #pragma unroll
    for (int i = 0; i < 8; ++i) {
        const int cc = i * 256 + t;            // 0..2047
        const int r = cc >> 3, slot = cc & 7;
        const int h = r >> 5, ls = r & 31;
        const float4 v = *(const float4*)(a_s + (r * 8 + (slot ^ (r & 7))) * 8);
        *(float4*)(O + ((size_t)(n * HNUM + h) * SDIM + s0 + ls) * DDIM + slot * 8) = v;
    }

    // fused transpose: valsT[n][h][d][s0..s0+31] from a_s (read-only now)
    if (m == 0) {
        #pragma unroll
        for (int i = 0; i < 2; ++i) {
            const int cid = i * 256 + t;       // 0..511 = h*64 + d
            const int hh = cid >> 6, d = cid & 63;
            union { ushort u[32]; float4 f[4]; } col;
            #pragma unroll
            for (int ls = 0; ls < 32; ++ls) {
                const int r = hh * 32 + ls;
                col.u[ls] = a_s[(r * 8 + ((d >> 3) ^ (r & 7))) * 8 + (d & 7)];
            }
            float4* dst = (float4*)(valsT_bf + ((size_t)(n * HNUM + hh) * DDIM + d) * SDIM + s0);
            dst[0] = col.f[0]; dst[1] = col.f[1]; dst[2] = col.f[2]; dst[3] = col.f[3];
        }
    }
}

// ---------------------------------------------------------------------------
__global__ __launch_bounds__(256) void conv_e(const float* __restrict__ E, ushort* __restrict__ e_bf) {
    const int i = blockIdx.x * 256 + threadIdx.x;
    e_bf[i] = bf16_of(E[i]);
}
__global__ __launch_bounds__(256) void conv_wo(const float* __restrict__ Wo, ushort* __restrict__ wo_bf) {
    const int i = blockIdx.x * 256 + threadIdx.x;
    wo_bf[i] = bf16_of(Wo[i]);
}

// ---------------------------------------------------------------------------
// Kernel B: MFMA attention — r5 structure + T14 register prefetch.
// Identical buffers/barriers/compute to the 84.6 µs kernel; ONLY change:
// tile jt+1's global loads are issued at the START of jt's compute phase
// (held in 5 float4 regs), and written to LDS between the barriers at the
// top of iteration jt+1. E-row offsets FIXED from r12: one row = 64 ushorts,
// so +64/+128 rows = +64*64 / +128*64 ushorts (r12 used *8 too many — OOB).
// ---------------------------------------------------------------------------
__global__ __launch_bounds__(512, 2) void attn_mfma(
    const ushort* __restrict__ vals_bf, const ushort* __restrict__ keys_bf,
    const ushort* __restrict__ qrs_bf, const ushort* __restrict__ valsT_bf,
    const ushort* __restrict__ e_bf, ushort* __restrict__ zh)
{
    __shared__ ushort k_s [64 * 64];    // 8 KB
    __shared__ ushort vt_s[64 * 64];    // 8 KB
    __shared__ ushort e_s [192 * 64];   // 24 KB  (union of both strips' windows)
    __shared__ ushort pe_s[128 * 64];   // 16 KB
    __shared__ ushort pb_s[128 * 64];   // 16 KB
    __shared__ float  vs_s[64];

    // XCD swizzle: same n -> same XCD (512 blocks = 8n * 8h * 8bt)
    const int vid = blockIdx.x;
    const int blk = (vid & 7) * 64 + (vid >> 3);
    const int bt = blk & 7, h = (blk >> 3) & 7, n = blk >> 6;
    const int i0 = bt * 128;
    const int t = threadIdx.x;
    const int w = t >> 6, l = t & 63, lrow = l & 15, lgrp = l >> 4;
    const int s = w >> 2, q = w & 3;
    const int myit = 2 * bt + s;
    const int eoff = (1 - s) * 64;      // strip's offset into the E union window

    const ushort* Qb  = qrs_bf   + (n * HNUM + h) * (SDIM * DDIM);
    const ushort* Kb  = keys_bf  + (n * HNUM + h) * (SDIM * DDIM);
    const ushort* Vb  = vals_bf  + (n * HNUM + h) * (SDIM * DDIM);
    const ushort* VTb = valsT_bf + (n * HNUM + h) * (SDIM * DDIM);

    // per-wave A-fragments (16 rows), loaded once
    bf16x8 a_q[2], a_vi[2];
    {
        const int grow = i0 + w * 16 + lrow;
        #pragma unroll
        for (int kc = 0; kc < 2; ++kc) {
            a_q[kc]  = *(const bf16x8*)(Qb + grow * DDIM + kc * 32 + lgrp * 8);
            a_vi[kc] = *(const bf16x8*)(Vb + grow * DDIM + kc * 32 + lgrp * 8);
        }
    }
    if (t < 64) vs_s[t] = 0.f;

    f32x4 accn[4], accz[4];
    #pragma unroll
    for (int f = 0; f < 4; ++f) {
        accn[f] = {0.f, 0.f, 0.f, 0.f};
        accz[f] = {0.f, 0.f, 0.f, 0.f};
    }
    float den[4] = {0.f, 0.f, 0.f, 0.f};

    // staging geometry (identical addressing to r5, split into load/write):
    // thread t owns VT/K chunk (srow, sslot) and E chunks (srow+64i, sslot).
    // Swizzle is row&7-invariant under +64, so E rows reuse sw + i*64*64.
    const int srow = t >> 3, sslot = t & 7;
    const int sw = (srow * 8 + (sslot ^ (srow & 7))) * 8;

    // prefetch registers (held across one iteration)
    float4 r_vt, r_k, r_e0, r_e1, r_e2;

    // ---- prologue: prefetch tile 0 ----
    {
        r_vt = *(const float4*)(VTb + srow * SDIM + sslot * 8);
        if (bt == 0)
            r_k = *(const float4*)(Kb + srow * DDIM + sslot * 8);
        {   // needE(0) always true
            const int ebU = SDIM - 128 - i0;
            const float4 z4 = make_float4(0.f, 0.f, 0.f, 0.f);
            int g = ebU + srow;
            r_e0 = (g < SDIM) ? *(const float4*)(e_bf + g * DDIM + sslot * 8) : z4;
            g += 64;
            r_e1 = (g < SDIM) ? *(const float4*)(e_bf + g * DDIM + sslot * 8) : z4;
            g += 64;
            r_e2 = (g < SDIM) ? *(const float4*)(e_bf + g * DDIM + sslot * 8) : z4;
        }
    }

    for (int jt = 0; jt < 16; ++jt) {
        const int j0 = jt * 64;
        const bool diag = (jt == myit);
        const bool needK = (jt >= 2 * bt);
        const bool needE = (jt <= 2 * bt + 1);
        __syncthreads();  // all waves done with vt/k/e from previous jt

        // ---- write prefetched tile jt (regs -> LDS; no global latency here) ----
        {
            *(float4*)(vt_s + sw) = r_vt;
            if (needK)
                *(float4*)(k_s + sw) = r_k;
            if (needE) {
                *(float4*)(e_s + sw)            = r_e0;
                *(float4*)(e_s + sw + 64 * 64)  = r_e1;   // +64 rows (64 ushort/row)
                *(float4*)(e_s + sw + 128 * 64) = r_e2;   // +128 rows
            }
        }
        __syncthreads();

        // ---- issue prefetch for tile jt+1 (covered by this compute phase) ----
        if (jt < 15) {
            const int j1 = j0 + 64;
            r_vt = *(const float4*)(VTb + srow * SDIM + j1 + sslot * 8);
            if (jt + 1 >= 2 * bt)
                r_k = *(const float4*)(Kb + (j1 + srow) * DDIM + sslot * 8);
            if (jt + 1 <= 2 * bt + 1) {
                const int ebU = SDIM - 128 - i0 + j1;
                const float4 z4 = make_float4(0.f, 0.f, 0.f, 0.f);
                int g = ebU + srow;
                r_e0 = (g < SDIM) ? *(const float4*)(e_bf + g * DDIM + sslot * 8) : z4;
                g += 64;
                r_e1 = (g < SDIM) ? *(const float4*)(e_bf + g * DDIM + sslot * 8) : z4;
                g += 64;
                r_e2 = (g < SDIM) ? *(const float4*)(e_bf + g * DDIM + sslot * 8) : z4;
            }
        }

        if (bt == 7 && t < 64) {  // block holding row S-1: accumulate col-sums of V
            float sum = 0.f;
            #pragma unroll
            for (int slot = 0; slot < 8; ++slot) {
                const bf16x8 vv = lds8(vt_s, t, slot);
                #pragma unroll
                for (int u = 0; u < 8; ++u) sum += f32_of((ushort)vv[u]);
            }
            vs_s[t] += sum;
        }

        // ---- QK side ----
        if (jt >= myit) {
            f32x4 sf[4];
            #pragma unroll
            for (int fc = 0; fc < 4; ++fc) sf[fc] = {0.f, 0.f, 0.f, 0.f};
            #pragma unroll
            for (int fc = 0; fc < 4; ++fc)
                if (!diag || fc >= q)   // diag: quadrants with all j<=i are dead
                    #pragma unroll
                    for (int kc = 0; kc < 2; ++kc)
                        sf[fc] = MFMA(a_q[kc], lds8(k_s, fc * 16 + lrow, lgrp + kc * 4), sf[fc]);
            #pragma unroll
            for (int fc = 0; fc < 4; ++fc) {
                #pragma unroll
                for (int r = 0; r < 4; ++r) {
                    const int rs = q * 16 + lgrp * 4 + r;   // strip-local row
                    const int col = fc * 16 + lrow;
                    float e = 0.f;
                    if (!diag || col > rs) e = __expf(sf[fc][r] * SCALE);
                    den[r] += e;
                    const int prow = w * 16 + lgrp * 4 + r;
                    pe_s[(prow * 8 + ((col >> 3) ^ (prow & 7))) * 8 + (col & 7)] = bf16_of(e);
                }
            }
            // PV (exp side): intra-wave LDS dependency only (no barrier)
            bf16x8 ap[2];
            #pragma unroll
            for (int kc = 0; kc < 2; ++kc) ap[kc] = lds8(pe_s, w * 16 + lrow, lgrp + kc * 4);
            #pragma unroll
            for (int fc = 0; fc < 4; ++fc)
                #pragma unroll
                for (int kc = 0; kc < 2; ++kc)
                    accn[fc] = MFMA(ap[kc], lds8(vt_s, fc * 16 + lrow, lgrp + kc * 4), accn[fc]);
        }

        // ---- band-bias side (two halves of 4 quadrants: lower peak VGPR) ----
        if (jt <= myit) {
            #pragma unroll
            for (int half = 0; half < 2; ++half) {
                f32x4 bd[4];
                #pragma unroll
                for (int fq = 0; fq < 4; ++fq) bd[fq] = {0.f, 0.f, 0.f, 0.f};
                #pragma unroll
                for (int fq = 0; fq < 4; ++fq) {
                    const int fc = half * 4 + fq;
                    const bool live = diag ? (fc <= 3 && fc + q >= 3)
                                           : (fc + q >= 3 && fc + q <= 7);
                    if (live)
                        #pragma unroll
                        for (int kc = 0; kc < 2; ++kc)
                            bd[fq] = MFMA(a_vi[kc], lds8(e_s, eoff + fc * 16 + lrow, lgrp + kc * 4), bd[fq]);
                }
                #pragma unroll
                for (int fq = 0; fq < 4; ++fq) {
                    const int fc = half * 4 + fq;
                    const bool touch = diag ? true : (fc + q >= 3 && fc + q <= 7);
                    if (touch) {
                        #pragma unroll
                        for (int r = 0; r < 4; ++r) {
                            const int rs = q * 16 + lgrp * 4 + r;
                            const int u = fc * 16 + lrow;
                            const int c = u - 63 + rs;
                            if (c >= 0 && c < 64) {
                                const float val = (diag && u > 63) ? 0.f : bd[fq][r];
                                const int prow = w * 16 + lgrp * 4 + r;
                                pb_s[(prow * 8 + ((c >> 3) ^ (prow & 7))) * 8 + (c & 7)] = bf16_of(val);
                            }
                        }
                    }
                }
            }
            // PV (bias side)
            bf16x8 ap[2];
            #pragma unroll
            for (int kc = 0; kc < 2; ++kc) ap[kc] = lds8(pb_s, w * 16 + lrow, lgrp + kc * 4);
            #pragma unroll
            for (int fc = 0; fc < 4; ++fc)
                #pragma unroll
                for (int kc = 0; kc < 2; ++kc)
                    accz[fc] = MFMA(ap[kc], lds8(vt_s, fc * 16 + lrow, lgrp + kc * 4), accz[fc]);
        }
    }

    __syncthreads();  // vs_s visibility

    #pragma unroll
    for (int r = 0; r < 4; ++r) {
        float d = den[r];
        d += __shfl_xor(d, 1);
        d += __shfl_xor(d, 2);
        d += __shfl_xor(d, 4);
        d += __shfl_xor(d, 8);
        den[r] = d;
    }

    #pragma unroll
    for (int fc = 0; fc < 4; ++fc) {
        #pragma unroll
        for (int r = 0; r < 4; ++r) {
            const int grow = i0 + w * 16 + lgrp * 4 + r;
            const int col = fc * 16 + lrow;
            float o;
            if (grow == SDIM - 1)
                o = vs_s[col] * (1.0f / SDIM) + accz[fc][r];
            else
                o = accn[fc][r] / den[r] + accz[fc][r];
            zh[(size_t)(n * SDIM + grow) * EMBD + h * DDIM + col] = bf16_of(o);
        }
    }
}

// ---------------------------------------------------------------------------
// Kernel C (MFMA): out = zh @ Wo.T + bo.  128x64 tiles, K=512.
// ---------------------------------------------------------------------------
__global__ __launch_bounds__(256) void out_mfma(
    const ushort* __restrict__ zh, const ushort* __restrict__ wo_bf,
    const float* __restrict__ bo, float* __restrict__ out)
{
    __shared__ ushort ah_s[128 * 64];  // 16 KB
    __shared__ ushort b_s [64 * 64];   // 8 KB

    const int vid = blockIdx.x;                 // 512 blocks
    const int blk = (vid & 7) * 64 + (vid >> 3);
    const int r0 = (blk >> 3) * 128, c0 = (blk & 7) * 64;
    const int t = threadIdx.x;
    const int w = t >> 6, l = t & 63, lrow = l & 15, lgrp = l >> 4;

    f32x4 acc[2][4];
    #pragma unroll
    for (int fr = 0; fr < 2; ++fr)
        #pragma unroll
        for (int fc = 0; fc < 4; ++fc) acc[fr][fc] = {0.f, 0.f, 0.f, 0.f};

    for (int kt = 0; kt < 8; ++kt) {
        __syncthreads();
        #pragma unroll
        for (int i = 0; i < 4; ++i) {
            const int cc = i * 256 + t;         // 0..1023
            const int r = cc >> 3, slot = cc & 7;
            const size_t src = (size_t)(r0 + r) * EMBD + kt * 64 + slot * 8;
            *(float4*)(ah_s + (r * 8 + (slot ^ (r & 7))) * 8) = *(const float4*)(zh + src);
        }
        #pragma unroll
        for (int i = 0; i < 2; ++i) {
            const int cc = i * 256 + t;         // 0..511
            const int r = cc >> 3, slot = cc & 7;
            const float4 vb = *(const float4*)(wo_bf + (size_t)(c0 + r) * EMBD + kt * 64 + slot * 8);
            *(float4*)(b_s + (r * 8 + (slot ^ (r & 7))) * 8) = vb;
        }
        __syncthreads();

        #pragma unroll
        for (int kc = 0; kc < 2; ++kc)
            #pragma unroll
            for (int fc = 0; fc < 4; ++fc) {
                const bf16x8 bfr = lds8(b_s, fc * 16 + lrow, lgrp + kc * 4);
                #pragma unroll
                for (int fr = 0; fr < 2; ++fr)
                    acc[fr][fc] = MFMA(lds8(ah_s, w * 32 + fr * 16 + lrow, lgrp + kc * 4), bfr, acc[fr][fc]);
            }
    }

    float bias[4];
    #pragma unroll
    for (int fc = 0; fc < 4; ++fc) bias[fc] = bo[c0 + fc * 16 + lrow];
    #pragma unroll
    for (int fr = 0; fr < 2; ++fr)
        #pragma unroll
        for (int fc = 0; fc < 4; ++fc)
            #pragma unroll
            for (int reg = 0; reg < 4; ++reg) {
                const int row = r0 + w * 32 + fr * 16 + lgrp * 4 + reg;
                const int col = c0 + fc * 16 + lrow;
                out[(size_t)row * EMBD + col] = acc[fr][fc][reg] + bias[fc];
            }
}

// ---------------------------------------------------------------------------
extern "C" void kernel_launch(void* const* d_in, const int* in_sizes, int n_in,
                              void* d_out, int out_size, void* d_ws, size_t ws_size,
                              hipStream_t stream) {
    const float* v  = (const float*)d_in[0];
    const float* k  = (const float*)d_in[1];
    const float* q  = (const float*)d_in[2];
    const float* Wv = (const float*)d_in[3];
    const float* bv = (const float*)d_in[4];
    const float* Wk = (const float*)d_in[5];
    const float* bk = (const float*)d_in[6];
    const float* Wq = (const float*)d_in[7];
    const float* bq = (const float*)d_in[8];
    const float* E  = (const float*)d_in[9];
    const float* Wo = (const float*)d_in[10];
    const float* bo = (const float*)d_in[11];
    float* out = (float*)d_out;

    char* ws = (char*)d_ws;
    ushort* qrs_bf   = (ushort*)(ws);                       // 8 MB
    ushort* keys_bf  = (ushort*)(ws + ((size_t)8 << 20));   // 8 MB
    ushort* vals_bf  = (ushort*)(ws + ((size_t)16 << 20));  // 8 MB
    ushort* valsT_bf = (ushort*)(ws + ((size_t)24 << 20));  // 8 MB
    ushort* e_bf     = (ushort*)(ws + ((size_t)32 << 20));  // 128 KB
    ushort* wo_bf    = (ushort*)(ws + ((size_t)33 << 20));  // 512 KB
    ushort* zh       = (ushort*)(ws + ((size_t)34 << 20));  // 8 MB

    proj_mfma<<<768, 256, 0, stream>>>(v, k, q, Wv, bv, Wk, bk, Wq, bq,
                                       vals_bf, keys_bf, qrs_bf, valsT_bf);
    conv_e<<<(SDIM * DDIM) / 256, 256, 0, stream>>>(E, e_bf);
    conv_wo<<<(EMBD * EMBD) / 256, 256, 0, stream>>>(Wo, wo_bf);
    attn_mfma<<<512, 512, 0, stream>>>(vals_bf, keys_bf, qrs_bf,
                                       valsT_bf, e_bf, zh);
    out_mfma<<<512, 256, 0, stream>>>(zh, wo_bf, bo, out);
}

// Round 14
// 111.209 us; speedup vs baseline: 1.0699x; 1.0699x over previous
//
#include <hip/hip_runtime.h>
#include <hip/hip_bf16.h>

#define SDIM 1024
#define HNUM 8
#define DDIM 64
#define EMBD 512
#define NBATCH 8

static constexpr float SCALE = 0.044194173824159216f; // 1/sqrt(512)

typedef short bf16x8 __attribute__((ext_vector_type(8)));
typedef float f32x4 __attribute__((ext_vector_type(4)));

__device__ __forceinline__ ushort bf16_of(float f) {
    return __builtin_bit_cast(unsigned short, __float2bfloat16(f));
}
__device__ __forceinline__ float f32_of(ushort u) {
    return __bfloat162float(__builtin_bit_cast(__hip_bfloat16, u));
}

// swizzled LDS tile access: rows of 64 bf16 = 8 chunks of 16B; chunk (row,slot)
// stored at slot ^ (row&7) -> conflict-free ds_read_b128 column walks.
__device__ __forceinline__ bf16x8 lds8(const ushort* base, int row, int slot) {
    return *(const bf16x8*)(base + (row * 8 + (slot ^ (row & 7))) * 8);
}

#define MFMA(a, b, c) __builtin_amdgcn_mfma_f32_16x16x32_bf16(a, b, c, 0, 0, 0)

// ---------------------------------------------------------------------------
// Kernel A (MFMA): per-head projections -> bf16, h-major layout [n][h][s][d].
// m==0 blocks additionally emit the transposed V panels [n][h][d][s].
// ---------------------------------------------------------------------------
__global__ __launch_bounds__(256) void proj_mfma(
    const float* __restrict__ xv, const float* __restrict__ xk, const float* __restrict__ xq,
    const float* __restrict__ Wv, const float* __restrict__ bv,
    const float* __restrict__ Wk, const float* __restrict__ bk,
    const float* __restrict__ Wq, const float* __restrict__ bq,
    ushort* __restrict__ vals_bf, ushort* __restrict__ keys_bf, ushort* __restrict__ qrs_bf,
    ushort* __restrict__ valsT_bf)
{
    __shared__ ushort a_s[256 * 64];   // 32 KB (also reused for C)
    __shared__ ushort w_s[64 * 64];    // 8 KB

    const int blk = blockIdx.x;        // 768 = 3 * 256
    const int m = blk % 3;
    const int chunk = blk / 3;
    const int tok0 = chunk * 32;
    const int n = tok0 >> 10, s0 = tok0 & 1023;
    const int t = threadIdx.x;
    const int w = t >> 6, l = t & 63, lrow = l & 15, lgrp = l >> 4;

    const float* X = (m == 0) ? xv : (m == 1) ? xk : xq;
    const float* W = (m == 0) ? Wv : (m == 1) ? Wk : Wq;
    const float* B = (m == 0) ? bv : (m == 1) ? bk : bq;
    ushort* O = (m == 0) ? vals_bf : (m == 1) ? keys_bf : qrs_bf;

    #pragma unroll
    for (int i = 0; i < 16; ++i) {
        const int f4 = i * 256 + t;            // 0..4095
        const int ls = f4 >> 7, c4 = f4 & 127;
        const int h = c4 >> 4, d4 = c4 & 15;
        const float4 v = ((const float4*)(X + (size_t)(tok0 + ls) * EMBD))[c4];
        ushort4 u;
        u.x = bf16_of(v.x); u.y = bf16_of(v.y); u.z = bf16_of(v.z); u.w = bf16_of(v.w);
        const int r = h * 32 + ls, slot = d4 >> 1;
        *(ushort4*)(a_s + (r * 8 + (slot ^ (r & 7))) * 8 + (d4 & 1) * 4) = u;
    }
    #pragma unroll
    for (int i = 0; i < 4; ++i) {
        const int f4 = i * 256 + t;            // 0..1023
        const int r = f4 >> 4, d4 = f4 & 15;
        const float4 v = ((const float4*)W)[f4];
        ushort4 u;
        u.x = bf16_of(v.x); u.y = bf16_of(v.y); u.z = bf16_of(v.z); u.w = bf16_of(v.w);
        const int slot = d4 >> 1;
        *(ushort4*)(w_s + (r * 8 + (slot ^ (r & 7))) * 8 + (d4 & 1) * 4) = u;
    }
    __syncthreads();

    f32x4 acc[4][4];
    #pragma unroll
    for (int fr = 0; fr < 4; ++fr)
        #pragma unroll
        for (int fc = 0; fc < 4; ++fc) acc[fr][fc] = {0.f, 0.f, 0.f, 0.f};

    bf16x8 af[4][2];
    #pragma unroll
    for (int fr = 0; fr < 4; ++fr)
        #pragma unroll
        for (int kc = 0; kc < 2; ++kc)
            af[fr][kc] = lds8(a_s, w * 64 + fr * 16 + lrow, lgrp + kc * 4);

    #pragma unroll
    for (int fc = 0; fc < 4; ++fc)
        #pragma unroll
        for (int kc = 0; kc < 2; ++kc) {
            const bf16x8 bfr = lds8(w_s, fc * 16 + lrow, lgrp + kc * 4);
            #pragma unroll
            for (int fr = 0; fr < 4; ++fr)
                acc[fr][fc] = MFMA(af[fr][kc], bfr, acc[fr][fc]);
        }
    __syncthreads();

    float bias[4];
    #pragma unroll
    for (int fc = 0; fc < 4; ++fc) bias[fc] = B[fc * 16 + lrow];
    #pragma unroll
    for (int fr = 0; fr < 4; ++fr)
        #pragma unroll
        for (int fc = 0; fc < 4; ++fc)
            #pragma unroll
            for (int reg = 0; reg < 4; ++reg) {
                const int row = w * 64 + fr * 16 + lgrp * 4 + reg;
                const int col = fc * 16 + lrow;
                a_s[(row * 8 + ((col >> 3) ^ (row & 7))) * 8 + (col & 7)] =
                    bf16_of(acc[fr][fc][reg] + bias[fc]);
            }
    __syncthreads();

    #pragma unroll
    for (int i = 0; i < 8; ++i) {
        const int cc = i * 256 + t;            // 0..2047
        const int r = cc >> 3, slot = cc & 7;
        const int h = r >> 5, ls = r & 31;
        const float4 v = *(const float4*)(a_s + (r * 8 + (slot ^ (r & 7))) * 8);
        *(float4*)(O + ((size_t)(n * HNUM + h) * SDIM + s0 + ls) * DDIM + slot * 8) = v;
    }

    // fused transpose: valsT[n][h][d][s0..s0+31] from a_s (read-only now)
    if (m == 0) {
        #pragma unroll
        for (int i = 0; i < 2; ++i) {
            const int cid = i * 256 + t;       // 0..511 = h*64 + d
            const int hh = cid >> 6, d = cid & 63;
            union { ushort u[32]; float4 f[4]; } col;
            #pragma unroll
            for (int ls = 0; ls < 32; ++ls) {
                const int r = hh * 32 + ls;
                col.u[ls] = a_s[(r * 8 + ((d >> 3) ^ (r & 7))) * 8 + (d & 7)];
            }
            float4* dst = (float4*)(valsT_bf + ((size_t)(n * HNUM + hh) * DDIM + d) * SDIM + s0);
            dst[0] = col.f[0]; dst[1] = col.f[1]; dst[2] = col.f[2]; dst[3] = col.f[3];
        }
    }
}

// ---------------------------------------------------------------------------
// merged E + Wo conversion (single launch): idx < S*D -> E, else Wo
// ---------------------------------------------------------------------------
__global__ __launch_bounds__(256) void conv_all(
    const float* __restrict__ E, const float* __restrict__ Wo,
    ushort* __restrict__ e_bf, ushort* __restrict__ wo_bf)
{
    const int i = blockIdx.x * 256 + threadIdx.x;   // 0 .. 327679
    if (i < SDIM * DDIM) {
        e_bf[i] = bf16_of(E[i]);
    } else {
        const int j = i - SDIM * DDIM;              // 0 .. EMBD*EMBD-1
        wo_bf[j] = bf16_of(Wo[j]);
    }
}

// ---------------------------------------------------------------------------
// Kernel B: MFMA attention — the validated 84.6 µs kernel (r5/r11 verbatim).
// 512 threads / 128 i-rows (two 64-row strips); K/VT/E fully staged per
// iteration; pe_s/pb_s split; launch_bounds(512,2) (proven no-spill).
// Seven structural alternatives (r6-r10, r12-r13) all measured slower.
// ---------------------------------------------------------------------------
__global__ __launch_bounds__(512, 2) void attn_mfma(
    const ushort* __restrict__ vals_bf, const ushort* __restrict__ keys_bf,
    const ushort* __restrict__ qrs_bf, const ushort* __restrict__ valsT_bf,
    const ushort* __restrict__ e_bf, ushort* __restrict__ zh)
{
    __shared__ ushort k_s [64 * 64];    // 8 KB
    __shared__ ushort vt_s[64 * 64];    // 8 KB
    __shared__ ushort e_s [192 * 64];   // 24 KB  (union of both strips' windows)
    __shared__ ushort pe_s[128 * 64];   // 16 KB
    __shared__ ushort pb_s[128 * 64];   // 16 KB
    __shared__ float  vs_s[64];

    // XCD swizzle: same n -> same XCD (512 blocks = 8n * 8h * 8bt)
    const int vid = blockIdx.x;
    const int blk = (vid & 7) * 64 + (vid >> 3);
    const int bt = blk & 7, h = (blk >> 3) & 7, n = blk >> 6;
    const int i0 = bt * 128;
    const int t = threadIdx.x;
    const int w = t >> 6, l = t & 63, lrow = l & 15, lgrp = l >> 4;
    const int s = w >> 2, q = w & 3;
    const int myit = 2 * bt + s;
    const int eoff = (1 - s) * 64;      // strip's offset into the E union window

    const ushort* Qb  = qrs_bf   + (n * HNUM + h) * (SDIM * DDIM);
    const ushort* Kb  = keys_bf  + (n * HNUM + h) * (SDIM * DDIM);
    const ushort* Vb  = vals_bf  + (n * HNUM + h) * (SDIM * DDIM);
    const ushort* VTb = valsT_bf + (n * HNUM + h) * (SDIM * DDIM);

    // per-wave A-fragments (16 rows), loaded once
    bf16x8 a_q[2], a_vi[2];
    {
        const int grow = i0 + w * 16 + lrow;
        #pragma unroll
        for (int kc = 0; kc < 2; ++kc) {
            a_q[kc]  = *(const bf16x8*)(Qb + grow * DDIM + kc * 32 + lgrp * 8);
            a_vi[kc] = *(const bf16x8*)(Vb + grow * DDIM + kc * 32 + lgrp * 8);
        }
    }
    if (t < 64) vs_s[t] = 0.f;

    f32x4 accn[4], accz[4];
    #pragma unroll
    for (int f = 0; f < 4; ++f) {
        accn[f] = {0.f, 0.f, 0.f, 0.f};
        accz[f] = {0.f, 0.f, 0.f, 0.f};
    }
    float den[4] = {0.f, 0.f, 0.f, 0.f};

    for (int jt = 0; jt < 16; ++jt) {
        const int j0 = jt * 64;
        const bool diag = (jt == myit);
        const bool needK = (jt >= 2 * bt);
        const bool needE = (jt <= 2 * bt + 1);
        __syncthreads();  // all waves done with vt/k/e from previous jt

        // ---- stage (512 threads) ----
        {
            const int row = t >> 3, slot = t & 7;
            const int sw = (row * 8 + (slot ^ (row & 7))) * 8;
            *(float4*)(vt_s + sw) = *(const float4*)(VTb + row * SDIM + j0 + slot * 8);
            if (needK)
                *(float4*)(k_s + sw) = *(const float4*)(Kb + (j0 + row) * DDIM + slot * 8);
        }
        if (needE) {
            const int ebU = SDIM - 128 - i0 + j0;
            #pragma unroll
            for (int i = 0; i < 3; ++i) {
                const int c = t + i * 512;          // 0..1535
                const int row = c >> 3, slot = c & 7;
                const int g = ebU + row;
                float4 vv = make_float4(0.f, 0.f, 0.f, 0.f);
                if (g < SDIM) vv = *(const float4*)(e_bf + g * DDIM + slot * 8);
                *(float4*)(e_s + (row * 8 + (slot ^ (row & 7))) * 8) = vv;
            }
        }
        __syncthreads();

        if (bt == 7 && t < 64) {  // block holding row S-1: accumulate col-sums of V
            float sum = 0.f;
            #pragma unroll
            for (int slot = 0; slot < 8; ++slot) {
                const bf16x8 vv = lds8(vt_s, t, slot);
                #pragma unroll
                for (int u = 0; u < 8; ++u) sum += f32_of((ushort)vv[u]);
            }
            vs_s[t] += sum;
        }

        // ---- QK side ----
        if (jt >= myit) {
            f32x4 sf[4];
            #pragma unroll
            for (int fc = 0; fc < 4; ++fc) sf[fc] = {0.f, 0.f, 0.f, 0.f};
            #pragma unroll
            for (int fc = 0; fc < 4; ++fc)
                if (!diag || fc >= q)   // diag: quadrants with all j<=i are dead
                    #pragma unroll
                    for (int kc = 0; kc < 2; ++kc)
                        sf[fc] = MFMA(a_q[kc], lds8(k_s, fc * 16 + lrow, lgrp + kc * 4), sf[fc]);
            #pragma unroll
            for (int fc = 0; fc < 4; ++fc) {
                #pragma unroll
                for (int r = 0; r < 4; ++r) {
                    const int rs = q * 16 + lgrp * 4 + r;   // strip-local row
                    const int col = fc * 16 + lrow;
                    float e = 0.f;
                    if (!diag || col > rs) e = __expf(sf[fc][r] * SCALE);
                    den[r] += e;
                    const int prow = w * 16 + lgrp * 4 + r;
                    pe_s[(prow * 8 + ((col >> 3) ^ (prow & 7))) * 8 + (col & 7)] = bf16_of(e);
                }
            }
            // PV (exp side): intra-wave LDS dependency only (no barrier)
            bf16x8 ap[2];
            #pragma unroll
            for (int kc = 0; kc < 2; ++kc) ap[kc] = lds8(pe_s, w * 16 + lrow, lgrp + kc * 4);
            #pragma unroll
            for (int fc = 0; fc < 4; ++fc)
                #pragma unroll
                for (int kc = 0; kc < 2; ++kc)
                    accn[fc] = MFMA(ap[kc], lds8(vt_s, fc * 16 + lrow, lgrp + kc * 4), accn[fc]);
        }

        // ---- band-bias side (two halves of 4 quadrants: lower peak VGPR) ----
        if (jt <= myit) {
            #pragma unroll
            for (int half = 0; half < 2; ++half) {
                f32x4 bd[4];
                #pragma unroll
                for (int fq = 0; fq < 4; ++fq) bd[fq] = {0.f, 0.f, 0.f, 0.f};
                #pragma unroll
                for (int fq = 0; fq < 4; ++fq) {
                    const int fc = half * 4 + fq;
                    const bool live = diag ? (fc <= 3 && fc + q >= 3)
                                           : (fc + q >= 3 && fc + q <= 7);
                    if (live)
                        #pragma unroll
                        for (int kc = 0; kc < 2; ++kc)
                            bd[fq] = MFMA(a_vi[kc], lds8(e_s, eoff + fc * 16 + lrow, lgrp + kc * 4), bd[fq]);
                }
                #pragma unroll
                for (int fq = 0; fq < 4; ++fq) {
                    const int fc = half * 4 + fq;
                    const bool touch = diag ? true : (fc + q >= 3 && fc + q <= 7);
                    if (touch) {
                        #pragma unroll
                        for (int r = 0; r < 4; ++r) {
                            const int rs = q * 16 + lgrp * 4 + r;
                            const int u = fc * 16 + lrow;
                            const int c = u - 63 + rs;
                            if (c >= 0 && c < 64) {
                                const float val = (diag && u > 63) ? 0.f : bd[fq][r];
                                const int prow = w * 16 + lgrp * 4 + r;
                                pb_s[(prow * 8 + ((c >> 3) ^ (prow & 7))) * 8 + (c & 7)] = bf16_of(val);
                            }
                        }
                    }
                }
            }
            // PV (bias side)
            bf16x8 ap[2];
            #pragma unroll
            for (int kc = 0; kc < 2; ++kc) ap[kc] = lds8(pb_s, w * 16 + lrow, lgrp + kc * 4);
            #pragma unroll
            for (int fc = 0; fc < 4; ++fc)
                #pragma unroll
                for (int kc = 0; kc < 2; ++kc)
                    accz[fc] = MFMA(ap[kc], lds8(vt_s, fc * 16 + lrow, lgrp + kc * 4), accz[fc]);
        }
    }

    __syncthreads();  // vs_s visibility

    #pragma unroll
    for (int r = 0; r < 4; ++r) {
        float d = den[r];
        d += __shfl_xor(d, 1);
        d += __shfl_xor(d, 2);
        d += __shfl_xor(d, 4);
        d += __shfl_xor(d, 8);
        den[r] = d;
    }

    #pragma unroll
    for (int fc = 0; fc < 4; ++fc) {
        #pragma unroll
        for (int r = 0; r < 4; ++r) {
            const int grow = i0 + w * 16 + lgrp * 4 + r;
            const int col = fc * 16 + lrow;
            float o;
            if (grow == SDIM - 1)
                o = vs_s[col] * (1.0f / SDIM) + accz[fc][r];
            else
                o = accn[fc][r] / den[r] + accz[fc][r];
            zh[(size_t)(n * SDIM + grow) * EMBD + h * DDIM + col] = bf16_of(o);
        }
    }
}

// ---------------------------------------------------------------------------
// Kernel C (MFMA): out = zh @ Wo.T + bo.  128x64 tiles, K=512.
// ---------------------------------------------------------------------------
__global__ __launch_bounds__(256) void out_mfma(
    const ushort* __restrict__ zh, const ushort* __restrict__ wo_bf,
    const float* __restrict__ bo, float* __restrict__ out)
{
    __shared__ ushort ah_s[128 * 64];  // 16 KB
    __shared__ ushort b_s [64 * 64];   // 8 KB

    const int vid = blockIdx.x;                 // 512 blocks
    const int blk = (vid & 7) * 64 + (vid >> 3);
    const int r0 = (blk >> 3) * 128, c0 = (blk & 7) * 64;
    const int t = threadIdx.x;
    const int w = t >> 6, l = t & 63, lrow = l & 15, lgrp = l >> 4;

    f32x4 acc[2][4];
    #pragma unroll
    for (int fr = 0; fr < 2; ++fr)
        #pragma unroll
        for (int fc = 0; fc < 4; ++fc) acc[fr][fc] = {0.f, 0.f, 0.f, 0.f};

    for (int kt = 0; kt < 8; ++kt) {
        __syncthreads();
        #pragma unroll
        for (int i = 0; i < 4; ++i) {
            const int cc = i * 256 + t;         // 0..1023
            const int r = cc >> 3, slot = cc & 7;
            const size_t src = (size_t)(r0 + r) * EMBD + kt * 64 + slot * 8;
            *(float4*)(ah_s + (r * 8 + (slot ^ (r & 7))) * 8) = *(const float4*)(zh + src);
        }
        #pragma unroll
        for (int i = 0; i < 2; ++i) {
            const int cc = i * 256 + t;         // 0..511
            const int r = cc >> 3, slot = cc & 7;
            const float4 vb = *(const float4*)(wo_bf + (size_t)(c0 + r) * EMBD + kt * 64 + slot * 8);
            *(float4*)(b_s + (r * 8 + (slot ^ (r & 7))) * 8) = vb;
        }
        __syncthreads();

        #pragma unroll
        for (int kc = 0; kc < 2; ++kc)
            #pragma unroll
            for (int fc = 0; fc < 4; ++fc) {
                const bf16x8 bfr = lds8(b_s, fc * 16 + lrow, lgrp + kc * 4);
                #pragma unroll
                for (int fr = 0; fr < 2; ++fr)
                    acc[fr][fc] = MFMA(lds8(ah_s, w * 32 + fr * 16 + lrow, lgrp + kc * 4), bfr, acc[fr][fc]);
            }
    }

    float bias[4];
    #pragma unroll
    for (int fc = 0; fc < 4; ++fc) bias[fc] = bo[c0 + fc * 16 + lrow];
    #pragma unroll
    for (int fr = 0; fr < 2; ++fr)
        #pragma unroll
        for (int fc = 0; fc < 4; ++fc)
            #pragma unroll
            for (int reg = 0; reg < 4; ++reg) {
                const int row = r0 + w * 32 + fr * 16 + lgrp * 4 + reg;
                const int col = c0 + fc * 16 + lrow;
                out[(size_t)row * EMBD + col] = acc[fr][fc][reg] + bias[fc];
            }
}

// ---------------------------------------------------------------------------
extern "C" void kernel_launch(void* const* d_in, const int* in_sizes, int n_in,
                              void* d_out, int out_size, void* d_ws, size_t ws_size,
                              hipStream_t stream) {
    const float* v  = (const float*)d_in[0];
    const float* k  = (const float*)d_in[1];
    const float* q  = (const float*)d_in[2];
    const float* Wv = (const float*)d_in[3];
    const float* bv = (const float*)d_in[4];
    const float* Wk = (const float*)d_in[5];
    const float* bk = (const float*)d_in[6];
    const float* Wq = (const float*)d_in[7];
    const float* bq = (const float*)d_in[8];
    const float* E  = (const float*)d_in[9];
    const float* Wo = (const float*)d_in[10];
    const float* bo = (const float*)d_in[11];
    float* out = (float*)d_out;

    char* ws = (char*)d_ws;
    ushort* qrs_bf   = (ushort*)(ws);                       // 8 MB
    ushort* keys_bf  = (ushort*)(ws + ((size_t)8 << 20));   // 8 MB
    ushort* vals_bf  = (ushort*)(ws + ((size_t)16 << 20));  // 8 MB
    ushort* valsT_bf = (ushort*)(ws + ((size_t)24 << 20));  // 8 MB
    ushort* e_bf     = (ushort*)(ws + ((size_t)32 << 20));  // 128 KB
    ushort* wo_bf    = (ushort*)(ws + ((size_t)33 << 20));  // 512 KB
    ushort* zh       = (ushort*)(ws + ((size_t)34 << 20));  // 8 MB

    proj_mfma<<<768, 256, 0, stream>>>(v, k, q, Wv, bv, Wk, bk, Wq, bq,
                                       vals_bf, keys_bf, qrs_bf, valsT_bf);
    conv_all<<<(SDIM * DDIM + EMBD * EMBD) / 256, 256, 0, stream>>>(E, Wo, e_bf, wo_bf);
    attn_mfma<<<512, 512, 0, stream>>>(vals_bf, keys_bf, qrs_bf,
                                       valsT_bf, e_bf, zh);
    out_mfma<<<512, 256, 0, stream>>>(zh, wo_bf, bo, out);
}

// Round 15
// 108.645 us; speedup vs baseline: 1.0952x; 1.0236x over previous
//
#include <hip/hip_runtime.h>
#include <hip/hip_bf16.h>

#define SDIM 1024
#define HNUM 8
#define DDIM 64
#define EMBD 512
#define NBATCH 8

static constexpr float SCALE = 0.044194173824159216f; // 1/sqrt(512)

typedef short bf16x8 __attribute__((ext_vector_type(8)));
typedef float f32x4 __attribute__((ext_vector_type(4)));

__device__ __forceinline__ ushort bf16_of(float f) {
    return __builtin_bit_cast(unsigned short, __float2bfloat16(f));
}
__device__ __forceinline__ float f32_of(ushort u) {
    return __bfloat162float(__builtin_bit_cast(__hip_bfloat16, u));
}

// swizzled LDS tile access: rows of 64 bf16 = 8 chunks of 16B; chunk (row,slot)
// stored at slot ^ (row&7) -> conflict-free ds_read_b128 column walks.
__device__ __forceinline__ bf16x8 lds8(const ushort* base, int row, int slot) {
    return *(const bf16x8*)(base + (row * 8 + (slot ^ (row & 7))) * 8);
}

#define MFMA(a, b, c) __builtin_amdgcn_mfma_f32_16x16x32_bf16(a, b, c, 0, 0, 0)

// ---------------------------------------------------------------------------
// Kernel A (MFMA): per-head projections -> bf16, h-major layout [n][h][s][d].
// m==0 blocks additionally emit the transposed V panels [n][h][d][s].
// Blocks >= 768 instead perform the E/Wo fp32->bf16 conversion (fused launch).
// ---------------------------------------------------------------------------
__global__ __launch_bounds__(256) void proj_mfma(
    const float* __restrict__ xv, const float* __restrict__ xk, const float* __restrict__ xq,
    const float* __restrict__ Wv, const float* __restrict__ bv,
    const float* __restrict__ Wk, const float* __restrict__ bk,
    const float* __restrict__ Wq, const float* __restrict__ bq,
    const float* __restrict__ E, const float* __restrict__ Wo,
    ushort* __restrict__ vals_bf, ushort* __restrict__ keys_bf, ushort* __restrict__ qrs_bf,
    ushort* __restrict__ valsT_bf, ushort* __restrict__ e_bf, ushort* __restrict__ wo_bf)
{
    __shared__ ushort a_s[256 * 64];   // 32 KB (also reused for C)
    __shared__ ushort w_s[64 * 64];    // 8 KB

    const int blk = blockIdx.x;        // 2048 = 768 proj + 1280 conv
    const int t = threadIdx.x;

    if (blk >= 768) {                  // fused E/Wo conversion
        const int i = (blk - 768) * 256 + t;   // 0 .. 327679
        if (i < SDIM * DDIM) {
            e_bf[i] = bf16_of(E[i]);
        } else {
            const int j = i - SDIM * DDIM;
            wo_bf[j] = bf16_of(Wo[j]);
        }
        return;
    }

    const int m = blk % 3;
    const int chunk = blk / 3;
    const int tok0 = chunk * 32;
    const int n = tok0 >> 10, s0 = tok0 & 1023;
    const int w = t >> 6, l = t & 63, lrow = l & 15, lgrp = l >> 4;

    const float* X = (m == 0) ? xv : (m == 1) ? xk : xq;
    const float* W = (m == 0) ? Wv : (m == 1) ? Wk : Wq;
    const float* B = (m == 0) ? bv : (m == 1) ? bk : bq;
    ushort* O = (m == 0) ? vals_bf : (m == 1) ? keys_bf : qrs_bf;

    #pragma unroll
    for (int i = 0; i < 16; ++i) {
        const int f4 = i * 256 + t;            // 0..4095
        const int ls = f4 >> 7, c4 = f4 & 127;
        const int h = c4 >> 4, d4 = c4 & 15;
        const float4 v = ((const float4*)(X + (size_t)(tok0 + ls) * EMBD))[c4];
        ushort4 u;
        u.x = bf16_of(v.x); u.y = bf16_of(v.y); u.z = bf16_of(v.z); u.w = bf16_of(v.w);
        const int r = h * 32 + ls, slot = d4 >> 1;
        *(ushort4*)(a_s + (r * 8 + (slot ^ (r & 7))) * 8 + (d4 & 1) * 4) = u;
    }
    #pragma unroll
    for (int i = 0; i < 4; ++i) {
        const int f4 = i * 256 + t;            // 0..1023
        const int r = f4 >> 4, d4 = f4 & 15;
        const float4 v = ((const float4*)W)[f4];
        ushort4 u;
        u.x = bf16_of(v.x); u.y = bf16_of(v.y); u.z = bf16_of(v.z); u.w = bf16_of(v.w);
        const int slot = d4 >> 1;
        *(ushort4*)(w_s + (r * 8 + (slot ^ (r & 7))) * 8 + (d4 & 1) * 4) = u;
    }
    __syncthreads();

    f32x4 acc[4][4];
    #pragma unroll
    for (int fr = 0; fr < 4; ++fr)
        #pragma unroll
        for (int fc = 0; fc < 4; ++fc) acc[fr][fc] = {0.f, 0.f, 0.f, 0.f};

    bf16x8 af[4][2];
    #pragma unroll
    for (int fr = 0; fr < 4; ++fr)
        #pragma unroll
        for (int kc = 0; kc < 2; ++kc)
            af[fr][kc] = lds8(a_s, w * 64 + fr * 16 + lrow, lgrp + kc * 4);

    #pragma unroll
    for (int fc = 0; fc < 4; ++fc)
        #pragma unroll
        for (int kc = 0; kc < 2; ++kc) {
            const bf16x8 bfr = lds8(w_s, fc * 16 + lrow, lgrp + kc * 4);
            #pragma unroll
            for (int fr = 0; fr < 4; ++fr)
                acc[fr][fc] = MFMA(af[fr][kc], bfr, acc[fr][fc]);
        }
    __syncthreads();

    float bias[4];
    #pragma unroll
    for (int fc = 0; fc < 4; ++fc) bias[fc] = B[fc * 16 + lrow];
    #pragma unroll
    for (int fr = 0; fr < 4; ++fr)
        #pragma unroll
        for (int fc = 0; fc < 4; ++fc)
            #pragma unroll
            for (int reg = 0; reg < 4; ++reg) {
                const int row = w * 64 + fr * 16 + lgrp * 4 + reg;
                const int col = fc * 16 + lrow;
                a_s[(row * 8 + ((col >> 3) ^ (row & 7))) * 8 + (col & 7)] =
                    bf16_of(acc[fr][fc][reg] + bias[fc]);
            }
    __syncthreads();

    #pragma unroll
    for (int i = 0; i < 8; ++i) {
        const int cc = i * 256 + t;            // 0..2047
        const int r = cc >> 3, slot = cc & 7;
        const int h = r >> 5, ls = r & 31;
        const float4 v = *(const float4*)(a_s + (r * 8 + (slot ^ (r & 7))) * 8);
        *(float4*)(O + ((size_t)(n * HNUM + h) * SDIM + s0 + ls) * DDIM + slot * 8) = v;
    }

    // fused transpose: valsT[n][h][d][s0..s0+31] from a_s (read-only now)
    if (m == 0) {
        #pragma unroll
        for (int i = 0; i < 2; ++i) {
            const int cid = i * 256 + t;       // 0..511 = h*64 + d
            const int hh = cid >> 6, d = cid & 63;
            union { ushort u[32]; float4 f[4]; } col;
            #pragma unroll
            for (int ls = 0; ls < 32; ++ls) {
                const int r = hh * 32 + ls;
                col.u[ls] = a_s[(r * 8 + ((d >> 3) ^ (r & 7))) * 8 + (d & 7)];
            }
            float4* dst = (float4*)(valsT_bf + ((size_t)(n * HNUM + hh) * DDIM + d) * SDIM + s0);
            dst[0] = col.f[0]; dst[1] = col.f[1]; dst[2] = col.f[2]; dst[3] = col.f[3];
        }
    }
}

// ---------------------------------------------------------------------------
// Kernel B: MFMA attention — the validated 84.6 µs structure; pe_s/pb_s merged
// into a single p_s (per-wave rows, sides sequential per wave; pattern
// validated r6-r8). LDS 74240 -> 57856. All compute byte-identical to r14.
// ---------------------------------------------------------------------------
__global__ __launch_bounds__(512, 2) void attn_mfma(
    const ushort* __restrict__ vals_bf, const ushort* __restrict__ keys_bf,
    const ushort* __restrict__ qrs_bf, const ushort* __restrict__ valsT_bf,
    const ushort* __restrict__ e_bf, ushort* __restrict__ zh)
{
    __shared__ ushort k_s [64 * 64];    // 8 KB
    __shared__ ushort vt_s[64 * 64];    // 8 KB
    __shared__ ushort e_s [192 * 64];   // 24 KB  (union of both strips' windows)
    __shared__ ushort p_s [128 * 64];   // 16 KB  (merged pe/pb; per-wave rows)
    __shared__ float  vs_s[64];

    // XCD swizzle: same n -> same XCD (512 blocks = 8n * 8h * 8bt)
    const int vid = blockIdx.x;
    const int blk = (vid & 7) * 64 + (vid >> 3);
    const int bt = blk & 7, h = (blk >> 3) & 7, n = blk >> 6;
    const int i0 = bt * 128;
    const int t = threadIdx.x;
    const int w = t >> 6, l = t & 63, lrow = l & 15, lgrp = l >> 4;
    const int s = w >> 2, q = w & 3;
    const int myit = 2 * bt + s;
    const int eoff = (1 - s) * 64;      // strip's offset into the E union window

    const ushort* Qb  = qrs_bf   + (n * HNUM + h) * (SDIM * DDIM);
    const ushort* Kb  = keys_bf  + (n * HNUM + h) * (SDIM * DDIM);
    const ushort* Vb  = vals_bf  + (n * HNUM + h) * (SDIM * DDIM);
    const ushort* VTb = valsT_bf + (n * HNUM + h) * (SDIM * DDIM);

    // per-wave A-fragments (16 rows), loaded once
    bf16x8 a_q[2], a_vi[2];
    {
        const int grow = i0 + w * 16 + lrow;
        #pragma unroll
        for (int kc = 0; kc < 2; ++kc) {
            a_q[kc]  = *(const bf16x8*)(Qb + grow * DDIM + kc * 32 + lgrp * 8);
            a_vi[kc] = *(const bf16x8*)(Vb + grow * DDIM + kc * 32 + lgrp * 8);
        }
    }
    if (t < 64) vs_s[t] = 0.f;

    f32x4 accn[4], accz[4];
    #pragma unroll
    for (int f = 0; f < 4; ++f) {
        accn[f] = {0.f, 0.f, 0.f, 0.f};
        accz[f] = {0.f, 0.f, 0.f, 0.f};
    }
    float den[4] = {0.f, 0.f, 0.f, 0.f};

    for (int jt = 0; jt < 16; ++jt) {
        const int j0 = jt * 64;
        const bool diag = (jt == myit);
        const bool needK = (jt >= 2 * bt);
        const bool needE = (jt <= 2 * bt + 1);
        __syncthreads();  // all waves done with vt/k/e from previous jt

        // ---- stage (512 threads) ----
        {
            const int row = t >> 3, slot = t & 7;
            const int sw = (row * 8 + (slot ^ (row & 7))) * 8;
            *(float4*)(vt_s + sw) = *(const float4*)(VTb + row * SDIM + j0 + slot * 8);
            if (needK)
                *(float4*)(k_s + sw) = *(const float4*)(Kb + (j0 + row) * DDIM + slot * 8);
        }
        if (needE) {
            const int ebU = SDIM - 128 - i0 + j0;
            #pragma unroll
            for (int i = 0; i < 3; ++i) {
                const int c = t + i * 512;          // 0..1535
                const int row = c >> 3, slot = c & 7;
                const int g = ebU + row;
                float4 vv = make_float4(0.f, 0.f, 0.f, 0.f);
                if (g < SDIM) vv = *(const float4*)(e_bf + g * DDIM + slot * 8);
                *(float4*)(e_s + (row * 8 + (slot ^ (row & 7))) * 8) = vv;
            }
        }
        __syncthreads();

        if (bt == 7 && t < 64) {  // block holding row S-1: accumulate col-sums of V
            float sum = 0.f;
            #pragma unroll
            for (int slot = 0; slot < 8; ++slot) {
                const bf16x8 vv = lds8(vt_s, t, slot);
                #pragma unroll
                for (int u = 0; u < 8; ++u) sum += f32_of((ushort)vv[u]);
            }
            vs_s[t] += sum;
        }

        // ---- QK side ----
        if (jt >= myit) {
            f32x4 sf[4];
            #pragma unroll
            for (int fc = 0; fc < 4; ++fc) sf[fc] = {0.f, 0.f, 0.f, 0.f};
            #pragma unroll
            for (int fc = 0; fc < 4; ++fc)
                if (!diag || fc >= q)   // diag: quadrants with all j<=i are dead
                    #pragma unroll
                    for (int kc = 0; kc < 2; ++kc)
                        sf[fc] = MFMA(a_q[kc], lds8(k_s, fc * 16 + lrow, lgrp + kc * 4), sf[fc]);
            #pragma unroll
            for (int fc = 0; fc < 4; ++fc) {
                #pragma unroll
                for (int r = 0; r < 4; ++r) {
                    const int rs = q * 16 + lgrp * 4 + r;   // strip-local row
                    const int col = fc * 16 + lrow;
                    float e = 0.f;
                    if (!diag || col > rs) e = __expf(sf[fc][r] * SCALE);
                    den[r] += e;
                    const int prow = w * 16 + lgrp * 4 + r;
                    p_s[(prow * 8 + ((col >> 3) ^ (prow & 7))) * 8 + (col & 7)] = bf16_of(e);
                }
            }
            // PV (exp side): intra-wave LDS dependency only (no barrier)
            bf16x8 ap[2];
            #pragma unroll
            for (int kc = 0; kc < 2; ++kc) ap[kc] = lds8(p_s, w * 16 + lrow, lgrp + kc * 4);
            #pragma unroll
            for (int fc = 0; fc < 4; ++fc)
                #pragma unroll
                for (int kc = 0; kc < 2; ++kc)
                    accn[fc] = MFMA(ap[kc], lds8(vt_s, fc * 16 + lrow, lgrp + kc * 4), accn[fc]);
        }

        // ---- band-bias side (two halves of 4 quadrants: lower peak VGPR) ----
        if (jt <= myit) {
            #pragma unroll
            for (int half = 0; half < 2; ++half) {
                f32x4 bd[4];
                #pragma unroll
                for (int fq = 0; fq < 4; ++fq) bd[fq] = {0.f, 0.f, 0.f, 0.f};
                #pragma unroll
                for (int fq = 0; fq < 4; ++fq) {
                    const int fc = half * 4 + fq;
                    const bool live = diag ? (fc <= 3 && fc + q >= 3)
                                           : (fc + q >= 3 && fc + q <= 7);
                    if (live)
                        #pragma unroll
                        for (int kc = 0; kc < 2; ++kc)
                            bd[fq] = MFMA(a_vi[kc], lds8(e_s, eoff + fc * 16 + lrow, lgrp + kc * 4), bd[fq]);
                }
                #pragma unroll
                for (int fq = 0; fq < 4; ++fq) {
                    const int fc = half * 4 + fq;
                    const bool touch = diag ? true : (fc + q >= 3 && fc + q <= 7);
                    if (touch) {
                        #pragma unroll
                        for (int r = 0; r < 4; ++r) {
                            const int rs = q * 16 + lgrp * 4 + r;
                            const int u = fc * 16 + lrow;
                            const int c = u - 63 + rs;
                            if (c >= 0 && c < 64) {
                                const float val = (diag && u > 63) ? 0.f : bd[fq][r];
                                const int prow = w * 16 + lgrp * 4 + r;
                                p_s[(prow * 8 + ((c >> 3) ^ (prow & 7))) * 8 + (c & 7)] = bf16_of(val);
                            }
                        }
                    }
                }
            }
            // PV (bias side)
            bf16x8 ap[2];
            #pragma unroll
            for (int kc = 0; kc < 2; ++kc) ap[kc] = lds8(p_s, w * 16 + lrow, lgrp + kc * 4);
            #pragma unroll
            for (int fc = 0; fc < 4; ++fc)
                #pragma unroll
                for (int kc = 0; kc < 2; ++kc)
                    accz[fc] = MFMA(ap[kc], lds8(vt_s, fc * 16 + lrow, lgrp + kc * 4), accz[fc]);
        }
    }

    __syncthreads();  // vs_s visibility

    #pragma unroll
    for (int r = 0; r < 4; ++r) {
        float d = den[r];
        d += __shfl_xor(d, 1);
        d += __shfl_xor(d, 2);
        d += __shfl_xor(d, 4);
        d += __shfl_xor(d, 8);
        den[r] = d;
    }

    #pragma unroll
    for (int fc = 0; fc < 4; ++fc) {
        #pragma unroll
        for (int r = 0; r < 4; ++r) {
            const int grow = i0 + w * 16 + lgrp * 4 + r;
            const int col = fc * 16 + lrow;
            float o;
            if (grow == SDIM - 1)
                o = vs_s[col] * (1.0f / SDIM) + accz[fc][r];
            else
                o = accn[fc][r] / den[r] + accz[fc][r];
            zh[(size_t)(n * SDIM + grow) * EMBD + h * DDIM + col] = bf16_of(o);
        }
    }
}

// ---------------------------------------------------------------------------
// Kernel C (MFMA): out = zh @ Wo.T + bo.  128x64 tiles, K=512.
// ---------------------------------------------------------------------------
__global__ __launch_bounds__(256) void out_mfma(
    const ushort* __restrict__ zh, const ushort* __restrict__ wo_bf,
    const float* __restrict__ bo, float* __restrict__ out)
{
    __shared__ ushort ah_s[128 * 64];  // 16 KB
    __shared__ ushort b_s [64 * 64];   // 8 KB

    const int vid = blockIdx.x;                 // 512 blocks
    const int blk = (vid & 7) * 64 + (vid >> 3);
    const int r0 = (blk >> 3) * 128, c0 = (blk & 7) * 64;
    const int t = threadIdx.x;
    const int w = t >> 6, l = t & 63, lrow = l & 15, lgrp = l >> 4;

    f32x4 acc[2][4];
    #pragma unroll
    for (int fr = 0; fr < 2; ++fr)
        #pragma unroll
        for (int fc = 0; fc < 4; ++fc) acc[fr][fc] = {0.f, 0.f, 0.f, 0.f};

    for (int kt = 0; kt < 8; ++kt) {
        __syncthreads();
        #pragma unroll
        for (int i = 0; i < 4; ++i) {
            const int cc = i * 256 + t;         // 0..1023
            const int r = cc >> 3, slot = cc & 7;
            const size_t src = (size_t)(r0 + r) * EMBD + kt * 64 + slot * 8;
            *(float4*)(ah_s + (r * 8 + (slot ^ (r & 7))) * 8) = *(const float4*)(zh + src);
        }
        #pragma unroll
        for (int i = 0; i < 2; ++i) {
            const int cc = i * 256 + t;         // 0..511
            const int r = cc >> 3, slot = cc & 7;
            const float4 vb = *(const float4*)(wo_bf + (size_t)(c0 + r) * EMBD + kt * 64 + slot * 8);
            *(float4*)(b_s + (r * 8 + (slot ^ (r & 7))) * 8) = vb;
        }
        __syncthreads();

        #pragma unroll
        for (int kc = 0; kc < 2; ++kc)
            #pragma unroll
            for (int fc = 0; fc < 4; ++fc) {
                const bf16x8 bfr = lds8(b_s, fc * 16 + lrow, lgrp + kc * 4);
                #pragma unroll
                for (int fr = 0; fr < 2; ++fr)
                    acc[fr][fc] = MFMA(lds8(ah_s, w * 32 + fr * 16 + lrow, lgrp + kc * 4), bfr, acc[fr][fc]);
            }
    }

    float bias[4];
    #pragma unroll
    for (int fc = 0; fc < 4; ++fc) bias[fc] = bo[c0 + fc * 16 + lrow];
    #pragma unroll
    for (int fr = 0; fr < 2; ++fr)
        #pragma unroll
        for (int fc = 0; fc < 4; ++fc)
            #pragma unroll
            for (int reg = 0; reg < 4; ++reg) {
                const int row = r0 + w * 32 + fr * 16 + lgrp * 4 + reg;
                const int col = c0 + fc * 16 + lrow;
                out[(size_t)row * EMBD + col] = acc[fr][fc][reg] + bias[fc];
            }
}

// ---------------------------------------------------------------------------
extern "C" void kernel_launch(void* const* d_in, const int* in_sizes, int n_in,
                              void* d_out, int out_size, void* d_ws, size_t ws_size,
                              hipStream_t stream) {
    const float* v  = (const float*)d_in[0];
    const float* k  = (const float*)d_in[1];
    const float* q  = (const float*)d_in[2];
    const float* Wv = (const float*)d_in[3];
    const float* bv = (const float*)d_in[4];
    const float* Wk = (const float*)d_in[5];
    const float* bk = (const float*)d_in[6];
    const float* Wq = (const float*)d_in[7];
    const float* bq = (const float*)d_in[8];
    const float* E  = (const float*)d_in[9];
    const float* Wo = (const float*)d_in[10];
    const float* bo = (const float*)d_in[11];
    float* out = (float*)d_out;

    char* ws = (char*)d_ws;
    ushort* qrs_bf   = (ushort*)(ws);                       // 8 MB
    ushort* keys_bf  = (ushort*)(ws + ((size_t)8 << 20));   // 8 MB
    ushort* vals_bf  = (ushort*)(ws + ((size_t)16 << 20));  // 8 MB
    ushort* valsT_bf = (ushort*)(ws + ((size_t)24 << 20));  // 8 MB
    ushort* e_bf     = (ushort*)(ws + ((size_t)32 << 20));  // 128 KB
    ushort* wo_bf    = (ushort*)(ws + ((size_t)33 << 20));  // 512 KB
    ushort* zh       = (ushort*)(ws + ((size_t)34 << 20));  // 8 MB

    proj_mfma<<<2048, 256, 0, stream>>>(v, k, q, Wv, bv, Wk, bk, Wq, bq, E, Wo,
                                        vals_bf, keys_bf, qrs_bf, valsT_bf,
                                        e_bf, wo_bf);
    attn_mfma<<<512, 512, 0, stream>>>(vals_bf, keys_bf, qrs_bf,
                                       valsT_bf, e_bf, zh);
    out_mfma<<<512, 256, 0, stream>>>(zh, wo_bf, bo, out);
}